// Round 2
// baseline (5847.267 us; speedup 1.0000x reference)
//
#include <hip/hip_runtime.h>
#include <stdint.h>

#define V 4096
#define D 128
#define E 12288
#define NPAD 16384
#define HALF 8192
#define TARGET 2048
#define ROWU32 256   // 4096 fields * 2 bits = 256 u32 per row (1 KB)

// ws layout (bytes)
#define WS_N     0u                            // V*ROWU32*4 = 4 MB (2-bit matrix)
#define WS_PRI   (V * ROWU32 * 4u)             // V float
#define WS_KEYS  (WS_PRI + V * 4u)             // NPAD u64
#define WS_ALIVE (WS_KEYS + NPAD * 8u)         // V u8

__global__ void k_scatter(const int* __restrict__ edges, unsigned* __restrict__ n32) {
    int e = blockIdx.x * 256 + threadIdx.x;
    if (e < E) {
        int a = edges[e], b = edges[E + e];
        atomicOr(&n32[a * ROWU32 + (b >> 4)], 2u << ((b & 15) * 2));
        atomicOr(&n32[b * ROWU32 + (a >> 4)], 2u << ((a & 15) * 2));
    }
}

// numpy pairwise f32 sum for n=128: 8 strided accumulators, then
// ((r0+r1)+(r2+r3)) + ((r4+r5)+(r6+r7)). No FMA contraction.
__global__ void k_pri(const float* __restrict__ f, float* __restrict__ pri) {
    int v = blockIdx.x * 256 + threadIdx.x;
    if (v < V) {
        const float* p = f + v * D;
        float r[8];
#pragma unroll
        for (int j = 0; j < 8; j++) r[j] = __fmul_rn(p[j], p[j]);
        for (int i = 8; i < D; i += 8) {
#pragma unroll
            for (int j = 0; j < 8; j++)
                r[j] = __fadd_rn(r[j], __fmul_rn(p[i + j], p[i + j]));
        }
        float s01 = __fadd_rn(r[0], r[1]);
        float s23 = __fadd_rn(r[2], r[3]);
        float s45 = __fadd_rn(r[4], r[5]);
        float s67 = __fadd_rn(r[6], r[7]);
        pri[v] = __fadd_rn(__fadd_rn(s01, s23), __fadd_rn(s45, s67));
    }
}

__global__ void k_copy(const float* __restrict__ f, float* __restrict__ out) {
    int i = blockIdx.x * 256 + threadIdx.x;
    if (i < V * D) out[i] = f[i];
}

__global__ void k_mask(const uint8_t* __restrict__ aliveG, float* __restrict__ out) {
    int i = blockIdx.x * 256 + threadIdx.x;
    if (i < V * D) {
        if (!aliveG[i >> 7]) out[i] = 0.0f;
    }
}

__launch_bounds__(256)
__global__ void k_main(const int* __restrict__ edges, const float* __restrict__ priG,
                       unsigned* __restrict__ n32, unsigned long long* __restrict__ keys,
                       uint8_t* __restrict__ aliveG, float* __restrict__ out) {
    __shared__ union {
        unsigned long long srt[HALF];        // 64 KB (bitonic buffer)
        struct {
            unsigned pk[E];                  // 48 KB packed (v0<<16|v1) in sorted order
            uint8_t alive[V];                // 4 KB
        } g;
    } sh;
    const int tid = threadIdx.x;

    // ---- phase 1: build u64 keys = (bits(epri) << 32) | idx ; pads sort last ----
    for (int s = tid; s < NPAD; s += 256) {
        unsigned long long rec;
        if (s < E) {
            int a = edges[s], b = edges[E + s];
            float k = __fadd_rn(priG[a], priG[b]);   // epri >= 0 -> bits are monotone
            rec = ((unsigned long long)__float_as_uint(k) << 32) | (unsigned)s;
        } else {
            rec = (0xFFFFFFFFull << 32) | (unsigned)s;
        }
        keys[s] = rec;
    }
    __syncthreads();

    // ---- phase 2: bitonic sort each 8192 half in LDS (u64 keys unique => stable) ----
    for (int h = 0; h < 2; h++) {
        unsigned long long* base = keys + h * HALF;
        for (int s = tid; s < HALF; s += 256) sh.srt[s] = base[s];
        __syncthreads();
        for (int k = 2; k <= HALF; k <<= 1) {
            for (int j = k >> 1; j >= 1; j >>= 1) {
                for (int i = tid; i < HALF; i += 256) {
                    int ixj = i ^ j;
                    if (ixj > i) {
                        unsigned long long a = sh.srt[i], b = sh.srt[ixj];
                        bool up = ((i & k) == 0);
                        if ((a > b) == up) { sh.srt[i] = b; sh.srt[ixj] = a; }
                    }
                }
                __syncthreads();
            }
        }
        for (int s = tid; s < HALF; s += 256) base[s] = sh.srt[s];
        __syncthreads();
    }

    // ---- phase 3: merge-path the two sorted halves -> sh.g.pk[0..E) ----
    {
        const unsigned long long* A = keys;
        const unsigned long long* B = keys + HALF;
        for (int t = tid; t < (E / 64); t += 256) {
            int d = t * 64;
            int lo = d > HALF ? d - HALF : 0;
            int hi = d < HALF ? d : HALF;
            while (lo < hi) {
                int mid = (lo + hi) >> 1;
                if (A[mid] < B[d - 1 - mid]) lo = mid + 1; else hi = mid;
            }
            int ia = lo, ib = d - lo;
            int end = d + 64; if (end > E) end = E;
            for (int o = d; o < end; o++) {
                bool takeA = (ib >= HALF) || (ia < HALF && A[ia] < B[ib]);
                unsigned long long r = takeA ? A[ia++] : B[ib++];
                int e = (int)(r & 0xFFFFFFFFull);
                int a = edges[e], b = edges[E + e];
                sh.g.pk[o] = ((unsigned)a << 16) | (unsigned)b;
            }
        }
        for (int v = tid; v < V; v += 256) sh.g.alive[v] = 1;
    }
    __syncthreads();

    // ---- phase 4: greedy collapse, ONE wave, 64-wide speculative window ----
    if (tid < 64) {
        const int lane = tid;
        volatile uint8_t* aliveL = sh.g.alive;
        int cnt = V;
        bool done = false;
        for (int w = 0; w < E && !done; w += 64) {
            int e = w + lane;                       // E % 64 == 0, always valid
            unsigned pkv = sh.g.pk[e];
            int a = (int)(pkv >> 16), b = (int)(pkv & 0xFFFFu);
            bool av = aliveL[a] && aliveL[b];
            unsigned wv = n32[a * ROWU32 + (b >> 4)];
            bool flag = av && (((wv >> ((b & 15) * 2)) & 3u) == 2u);
            unsigned long long m = __ballot(flag);
            while (m) {
                int i = __ffsll((unsigned long long)m) - 1;
                int v0 = __shfl(a, i), v1 = __shfl(b, i);

                // features: f[v0] = 0.5*(f[v0]+f[v1]) ; 64 lanes x float2
                {
                    float2* fa = (float2*)(out + v0 * D);
                    float2* fb = (float2*)(out + v1 * D);
                    float2 x = fa[lane], y = fb[lane];
                    fa[lane] = make_float2(0.5f * (x.x + y.x), 0.5f * (x.y + y.y));
                }

                // row merge: 1 KB rows, one uint4 per lane; clamped 2-bit add:
                // r = a|b|((a&b&0xAAAAAAAA)>>1)   (values stay in {0,2,3})
                {
                    uint4* rA = (uint4*)(n32 + v0 * ROWU32);
                    uint4* rB = (uint4*)(n32 + v1 * ROWU32);
                    uint4 ra = rA[lane], rb = rB[lane];
                    uint4 rr;
                    rr.x = ra.x | rb.x | ((ra.x & rb.x & 0xAAAAAAAAu) >> 1);
                    rr.y = ra.y | rb.y | ((ra.y & rb.y & 0xAAAAAAAAu) >> 1);
                    rr.z = ra.z | rb.z | ((ra.z & rb.z & 0xAAAAAAAAu) >> 1);
                    rr.w = ra.w | rb.w | ((ra.w & rb.w & 0xAAAAAAAAu) >> 1);
                    // clear fields v0, v1 (diagonal / dead column) in row v0
                    if ((v0 >> 6) == lane) (&rr.x)[(v0 >> 4) & 3] &= ~(3u << ((v0 & 15) * 2));
                    if ((v1 >> 6) == lane) (&rr.x)[(v1 >> 4) & 3] &= ~(3u << ((v1 & 15) * 2));
                    rA[lane] = rr;
                    rB[lane] = make_uint4(0u, 0u, 0u, 0u);
                    // column fixups: rows x adjacent to v1 (b-field != 0), x not in {v0,v1}
#pragma unroll
                    for (int c = 0; c < 4; c++) {
                        unsigned bb = (&rb.x)[c];
                        if (!bb) continue;
                        unsigned rv = (&rr.x)[c];
                        int xbase = lane * 64 + c * 16;
                        unsigned t = bb;
                        while (t) {
                            int bit = __ffs(t) - 1;
                            int q = bit >> 1;
                            t &= ~(3u << (q * 2));
                            int x = xbase + q;
                            if (x != v0 && x != v1) {
                                unsigned fv = (rv >> (q * 2)) & 3u;  // new n[x][v0]
                                int w0 = x * ROWU32 + (v0 >> 4);
                                int w1 = x * ROWU32 + (v1 >> 4);
                                unsigned m0 = 3u << ((v0 & 15) * 2);
                                unsigned m1 = 3u << ((v1 & 15) * 2);
                                if (w0 == w1) {
                                    unsigned t0 = n32[w0];
                                    t0 = (t0 & ~(m0 | m1)) | (fv << ((v0 & 15) * 2));
                                    n32[w0] = t0;
                                } else {
                                    unsigned t0 = n32[w0];
                                    n32[w0] = (t0 & ~m0) | (fv << ((v0 & 15) * 2));
                                    unsigned t1 = n32[w1];
                                    n32[w1] = t1 & ~m1;
                                }
                            }
                        }
                    }
                }

                if (lane == 0) aliveL[v1] = 0;
                cnt--;
                if (cnt == TARGET) { done = true; break; }

                // drain stores (global + LDS) before rechecking lanes > i
                __builtin_amdgcn_s_waitcnt(0);
                av = av && (a != v1) && (b != v1);
                unsigned wv2 = n32[a * ROWU32 + (b >> 4)];
                bool f2 = av && (((wv2 >> ((b & 15) * 2)) & 3u) == 2u);
                flag = (lane > i) && f2;
                m = __ballot(flag);
            }
        }
        // outputs: alive (float) + cnt (float) + alive bytes for k_mask
        for (int v = lane; v < V; v += 64) {
            uint8_t ao = sh.g.alive[v];
            aliveG[v] = ao;
            out[V * D + v] = ao ? 1.0f : 0.0f;
        }
        if (lane == 0) out[V * D + V] = (float)cnt;
    }
}

extern "C" void kernel_launch(void* const* d_in, const int* in_sizes, int n_in,
                              void* d_out, int out_size, void* d_ws, size_t ws_size,
                              hipStream_t stream) {
    (void)in_sizes; (void)n_in; (void)out_size; (void)ws_size;
    const float* features = (const float*)d_in[0];
    const int* edges = (const int*)d_in[1];
    uint8_t* ws = (uint8_t*)d_ws;
    unsigned* n32 = (unsigned*)(ws + WS_N);
    float* pri = (float*)(ws + WS_PRI);
    unsigned long long* keys = (unsigned long long*)(ws + WS_KEYS);
    uint8_t* aliveG = ws + WS_ALIVE;
    float* out = (float*)d_out;

    hipMemsetAsync(n32, 0, (size_t)V * ROWU32 * 4, stream);
    k_scatter<<<(E + 255) / 256, 256, 0, stream>>>(edges, n32);
    k_pri<<<(V + 255) / 256, 256, 0, stream>>>(features, pri);
    k_copy<<<(V * D + 255) / 256, 256, 0, stream>>>(features, out);
    k_main<<<1, 256, 0, stream>>>(edges, pri, n32, keys, aliveG, out);
    k_mask<<<(V * D + 255) / 256, 256, 0, stream>>>(aliveG, out);
}

// Round 3
// 4049.350 us; speedup vs baseline: 1.4440x; 1.4440x over previous
//
#include <hip/hip_runtime.h>
#include <stdint.h>

#define V 4096
#define D 128
#define E 12288
#define NPAD 16384
#define HALF 8192
#define TARGET 2048
#define MAXM (V - TARGET)    // 2048 max merges
#define ROWU32 256           // 4096 fields * 2 bits = 256 u32 per row (1 KB)

// ws layout (bytes)
#define WS_N      0u                            // V*ROWU32*4 = 4 MB (2-bit matrix)
#define WS_PRI    (V * ROWU32 * 4u)             // V float
#define WS_KEYS   (WS_PRI + V * 4u)             // NPAD u64
#define WS_PAIRS  (WS_KEYS + NPAD * 8u)         // MAXM u32
#define WS_MCOUNT (WS_PAIRS + MAXM * 4u)        // 1 int

__global__ void k_scatter(const int* __restrict__ edges, unsigned* __restrict__ n32) {
    int e = blockIdx.x * 256 + threadIdx.x;
    if (e < E) {
        int a = edges[e], b = edges[E + e];
        atomicOr(&n32[a * ROWU32 + (b >> 4)], 2u << ((b & 15) * 2));
        atomicOr(&n32[b * ROWU32 + (a >> 4)], 2u << ((a & 15) * 2));
    }
}

// numpy pairwise f32 sum for n=128: 8 strided accumulators, then
// ((r0+r1)+(r2+r3)) + ((r4+r5)+(r6+r7)). No FMA contraction.
__global__ void k_pri(const float* __restrict__ f, float* __restrict__ pri) {
    int v = blockIdx.x * 256 + threadIdx.x;
    if (v < V) {
        const float* p = f + v * D;
        float r[8];
#pragma unroll
        for (int j = 0; j < 8; j++) r[j] = __fmul_rn(p[j], p[j]);
        for (int i = 8; i < D; i += 8) {
#pragma unroll
            for (int j = 0; j < 8; j++)
                r[j] = __fadd_rn(r[j], __fmul_rn(p[i + j], p[i + j]));
        }
        float s01 = __fadd_rn(r[0], r[1]);
        float s23 = __fadd_rn(r[2], r[3]);
        float s45 = __fadd_rn(r[4], r[5]);
        float s67 = __fadd_rn(r[6], r[7]);
        pri[v] = __fadd_rn(__fadd_rn(s01, s23), __fadd_rn(s45, s67));
    }
}

__launch_bounds__(256)
__global__ void k_main(const int* __restrict__ edges, const float* __restrict__ priG,
                       unsigned* __restrict__ n32, unsigned long long* __restrict__ keys,
                       unsigned* __restrict__ pairsG, int* __restrict__ mcountG,
                       float* __restrict__ out) {
    __shared__ union {
        unsigned long long srt[HALF];        // 64 KB (bitonic buffer)
        struct {
            unsigned pk[E];                  // 48 KB packed (v0<<16|v1) in sorted order
            uint8_t alive[V];                // 4 KB
            unsigned pairs[MAXM];            // 8 KB merge log
        } g;
    } sh;
    const int tid = threadIdx.x;

    // ---- phase 1: build u64 keys = (bits(epri) << 32) | idx ; pads sort last ----
    for (int s = tid; s < NPAD; s += 256) {
        unsigned long long rec;
        if (s < E) {
            int a = edges[s], b = edges[E + s];
            float k = __fadd_rn(priG[a], priG[b]);   // epri >= 0 -> bits are monotone
            rec = ((unsigned long long)__float_as_uint(k) << 32) | (unsigned)s;
        } else {
            rec = (0xFFFFFFFFull << 32) | (unsigned)s;
        }
        keys[s] = rec;
    }
    __syncthreads();

    // ---- phase 2: bitonic sort each 8192 half in LDS (u64 keys unique => stable) ----
    for (int h = 0; h < 2; h++) {
        unsigned long long* base = keys + h * HALF;
        for (int s = tid; s < HALF; s += 256) sh.srt[s] = base[s];
        __syncthreads();
        for (int k = 2; k <= HALF; k <<= 1) {
            for (int j = k >> 1; j >= 1; j >>= 1) {
                for (int i = tid; i < HALF; i += 256) {
                    int ixj = i ^ j;
                    if (ixj > i) {
                        unsigned long long a = sh.srt[i], b = sh.srt[ixj];
                        bool up = ((i & k) == 0);
                        if ((a > b) == up) { sh.srt[i] = b; sh.srt[ixj] = a; }
                    }
                }
                __syncthreads();
            }
        }
        for (int s = tid; s < HALF; s += 256) base[s] = sh.srt[s];
        __syncthreads();
    }

    // ---- phase 3: merge-path the two sorted halves -> sh.g.pk[0..E) ----
    {
        const unsigned long long* A = keys;
        const unsigned long long* B = keys + HALF;
        for (int t = tid; t < (E / 64); t += 256) {
            int d = t * 64;
            int lo = d > HALF ? d - HALF : 0;
            int hi = d < HALF ? d : HALF;
            while (lo < hi) {
                int mid = (lo + hi) >> 1;
                if (A[mid] < B[d - 1 - mid]) lo = mid + 1; else hi = mid;
            }
            int ia = lo, ib = d - lo;
            int end = d + 64; if (end > E) end = E;
            for (int o = d; o < end; o++) {
                bool takeA = (ib >= HALF) || (ia < HALF && A[ia] < B[ib]);
                unsigned long long r = takeA ? A[ia++] : B[ib++];
                int e = (int)(r & 0xFFFFFFFFull);
                int a = edges[e], b = edges[E + e];
                sh.g.pk[o] = ((unsigned)a << 16) | (unsigned)b;
            }
        }
        for (int v = tid; v < V; v += 256) sh.g.alive[v] = 1;
    }
    __syncthreads();

    // ---- phase 4: greedy collapse, ONE wave, 64-wide window,
    //      atomicXor fixups (no loads), register/shfl recheck (no memory) ----
    if (tid < 64) {
        const int lane = tid;
        volatile uint8_t* aliveL = sh.g.alive;
        int cnt = V;
        int mcount = 0;
        bool done = false;
        for (int w = 0; w < E && !done; w += 64) {
            int e = w + lane;                       // E % 64 == 0
            unsigned pkv = sh.g.pk[e];
            int a = (int)(pkv >> 16), b = (int)(pkv & 0xFFFFu);
            bool av = aliveL[a] && aliveL[b];
            unsigned wv = n32[a * ROWU32 + (b >> 4)];
            unsigned fv = (wv >> ((b & 15) * 2)) & 3u;   // cached field, kept fresh below
            unsigned long long m = __ballot(av && (fv == 2u));
            while (m) {
                int i = __ffsll((unsigned long long)m) - 1;
                int v0 = __shfl(a, i), v1 = __shfl(b, i);

                // row merge: clamped 2-bit add r = a|b|((a&b&0xAAAA..)>>1), values {0,2,3}
                uint4* rA = (uint4*)(n32 + v0 * ROWU32);
                uint4* rB = (uint4*)(n32 + v1 * ROWU32);
                uint4 ra = rA[lane], rb = rB[lane];
                uint4 rr;
                rr.x = ra.x | rb.x | ((ra.x & rb.x & 0xAAAAAAAAu) >> 1);
                rr.y = ra.y | rb.y | ((ra.y & rb.y & 0xAAAAAAAAu) >> 1);
                rr.z = ra.z | rb.z | ((ra.z & rb.z & 0xAAAAAAAAu) >> 1);
                rr.w = ra.w | rb.w | ((ra.w & rb.w & 0xAAAAAAAAu) >> 1);
                if ((v0 >> 6) == lane) (&rr.x)[(v0 >> 4) & 3] &= ~(3u << ((v0 & 15) * 2));
                if ((v1 >> 6) == lane) (&rr.x)[(v1 >> 4) & 3] &= ~(3u << ((v1 & 15) * 2));
                rA[lane] = rr;
                rB[lane] = make_uint4(0u, 0u, 0u, 0u);

                // column fixups via atomicXor, zero loads:
                // old n[x][v0] = n[v0][x] = ra field x; old n[x][v1] = rb field x (symmetry)
                {
                    int sh0 = (v0 & 15) * 2, sh1 = (v1 & 15) * 2;
                    int wi0 = v0 >> 4, wi1 = v1 >> 4;
#pragma unroll
                    for (int c = 0; c < 4; c++) {
                        unsigned bb = (&rb.x)[c];
                        if (!bb) continue;
                        unsigned aa = (&ra.x)[c];
                        unsigned vv = (&rr.x)[c];
                        int xbase = lane * 64 + c * 16;
                        unsigned t = bb;
                        while (t) {
                            int bit = __ffs(t) - 1;
                            int q = bit >> 1;
                            t &= ~(3u << (q * 2));
                            int x = xbase + q;
                            if (x == v0 || x == v1) continue;
                            unsigned o0  = (aa >> (q * 2)) & 3u;
                            unsigned o1  = (bb >> (q * 2)) & 3u;
                            unsigned val = (vv >> (q * 2)) & 3u;
                            unsigned* base = n32 + x * ROWU32;
                            if (wi0 == wi1) {
                                atomicXor(base + wi0, ((o0 ^ val) << sh0) | (o1 << sh1));
                            } else {
                                unsigned x0 = (o0 ^ val) << sh0;
                                if (x0) atomicXor(base + wi0, x0);
                                atomicXor(base + wi1, o1 << sh1);
                            }
                        }
                    }
                }

                if (lane == 0) {
                    aliveL[v1] = 0;
                    sh.g.pairs[mcount] = ((unsigned)v0 << 16) | (unsigned)v1;
                }
                mcount++;
                cnt--;
                if (cnt == TARGET) { done = true; break; }

                // recheck: pure registers + shfl. n[a][b] changed only if v0/v1 involved.
                av = av && (a != v1) && (b != v1);
                int tgt = (a == v0) ? b : ((b == v0) ? a : -1);
                int srcl = (tgt >= 0) ? (tgt >> 6) : 0;
                unsigned c0 = __shfl(rr.x, srcl), c1 = __shfl(rr.y, srcl);
                unsigned c2 = __shfl(rr.z, srcl), c3 = __shfl(rr.w, srcl);
                if (tgt >= 0) {
                    int ci = (tgt >> 4) & 3;
                    unsigned cw = (ci == 0) ? c0 : (ci == 1) ? c1 : (ci == 2) ? c2 : c3;
                    fv = (cw >> ((tgt & 15) * 2)) & 3u;
                }
                m = __ballot((lane > i) && av && (fv == 2u));
            }
        }
        // outputs: merge log -> global, alive floats, cnt
        for (int p = lane; p < mcount; p += 64) pairsG[p] = sh.g.pairs[p];
        if (lane == 0) mcountG[0] = mcount;
        for (int v = lane; v < V; v += 64)
            out[V * D + v] = sh.g.alive[v] ? 1.0f : 0.0f;
        if (lane == 0) out[V * D + V] = (float)cnt;
    }
}

// Replay the merge forest: per-vertex (root, weight), then scatter-add w*f[v] into out[root].
__launch_bounds__(256)
__global__ void k_apply(const float* __restrict__ f, const unsigned* __restrict__ pairsG,
                        const int* __restrict__ mcountG, float* __restrict__ out) {
    __shared__ unsigned pl[MAXM];
    __shared__ int rootL[256];
    __shared__ float wL[256];
    const int tid = threadIdx.x;
    const int mc = mcountG[0];
    for (int j = tid; j < mc; j += 256) pl[j] = pairsG[j];
    __syncthreads();
    int cur = blockIdx.x * 256 + tid;
    float w = 1.0f;
    for (int j = 0; j < mc; j++) {
        unsigned p = pl[j];
        int v0 = (int)(p >> 16), v1 = (int)(p & 0xFFFFu);
        if (cur == v1) { cur = v0; w *= 0.5f; }
        else if (cur == v0) w *= 0.5f;
    }
    rootL[tid] = cur;
    wL[tid] = w;
    __syncthreads();
    const int sub = tid >> 7;     // 2 vertices per iteration
    const int d = tid & 127;
    for (int s = 0; s < 256; s += 2) {
        int idx = s + sub;
        int vv = blockIdx.x * 256 + idx;
        atomicAdd(&out[rootL[idx] * D + d], wL[idx] * f[vv * D + d]);
    }
}

extern "C" void kernel_launch(void* const* d_in, const int* in_sizes, int n_in,
                              void* d_out, int out_size, void* d_ws, size_t ws_size,
                              hipStream_t stream) {
    (void)in_sizes; (void)n_in; (void)out_size; (void)ws_size;
    const float* features = (const float*)d_in[0];
    const int* edges = (const int*)d_in[1];
    uint8_t* ws = (uint8_t*)d_ws;
    unsigned* n32 = (unsigned*)(ws + WS_N);
    float* pri = (float*)(ws + WS_PRI);
    unsigned long long* keys = (unsigned long long*)(ws + WS_KEYS);
    unsigned* pairsG = (unsigned*)(ws + WS_PAIRS);
    int* mcountG = (int*)(ws + WS_MCOUNT);
    float* out = (float*)d_out;

    hipMemsetAsync(n32, 0, (size_t)V * ROWU32 * 4, stream);
    hipMemsetAsync(out, 0, (size_t)V * D * sizeof(float), stream);
    k_scatter<<<(E + 255) / 256, 256, 0, stream>>>(edges, n32);
    k_pri<<<(V + 255) / 256, 256, 0, stream>>>(features, pri);
    k_main<<<1, 256, 0, stream>>>(edges, pri, n32, keys, pairsG, mcountG, out);
    k_apply<<<V / 256, 256, 0, stream>>>(features, pairsG, mcountG, out);
}

// Round 4
// 3482.273 us; speedup vs baseline: 1.6792x; 1.1628x over previous
//
#include <hip/hip_runtime.h>
#include <stdint.h>

#define V 4096
#define D 128
#define E 12288
#define NPAD 16384
#define HALF 8192
#define TARGET 2048
#define MAXM (V - TARGET)    // 2048 max merges
#define ROWU32 256           // 4096 fields * 2 bits = 256 u32 per row (1 KB)

// ws layout (bytes)
#define WS_N      0u                            // V*ROWU32*4 = 4 MB (2-bit matrix)
#define WS_PRI    (V * ROWU32 * 4u)             // V float
#define WS_KEYS   (WS_PRI + V * 4u)             // NPAD u64
#define WS_PK     (WS_KEYS + NPAD * 8u)         // E u32 (sorted packed edges)
#define WS_PAIRS  (WS_PK + E * 4u)              // MAXM u32
#define WS_MCOUNT (WS_PAIRS + MAXM * 4u)        // 1 int
#define WS_ALIVE  (WS_MCOUNT + 16u)             // V u8

__device__ __forceinline__ unsigned getf(const uint4& r, int c) {
    unsigned lo = (c & 2) ? r.z : r.x;
    unsigned hi = (c & 2) ? r.w : r.y;
    return (c & 1) ? hi : lo;
}

__global__ void k_scatter(const int* __restrict__ edges, unsigned* __restrict__ n32) {
    int e = blockIdx.x * 256 + threadIdx.x;
    if (e < E) {
        int a = edges[e], b = edges[E + e];
        atomicOr(&n32[a * ROWU32 + (b >> 4)], 2u << ((b & 15) * 2));
        atomicOr(&n32[b * ROWU32 + (a >> 4)], 2u << ((a & 15) * 2));
    }
}

// numpy pairwise f32 sum for n=128 (matches np oracle reduction order)
__global__ void k_pri(const float* __restrict__ f, float* __restrict__ pri) {
    int v = blockIdx.x * 256 + threadIdx.x;
    if (v < V) {
        const float* p = f + v * D;
        float r[8];
#pragma unroll
        for (int j = 0; j < 8; j++) r[j] = __fmul_rn(p[j], p[j]);
        for (int i = 8; i < D; i += 8) {
#pragma unroll
            for (int j = 0; j < 8; j++)
                r[j] = __fadd_rn(r[j], __fmul_rn(p[i + j], p[i + j]));
        }
        float s01 = __fadd_rn(r[0], r[1]);
        float s23 = __fadd_rn(r[2], r[3]);
        float s45 = __fadd_rn(r[4], r[5]);
        float s67 = __fadd_rn(r[6], r[7]);
        pri[v] = __fadd_rn(__fadd_rn(s01, s23), __fadd_rn(s45, s67));
    }
}

__global__ void k_keys(const int* __restrict__ edges, const float* __restrict__ pri,
                       unsigned long long* __restrict__ keys) {
    int s = blockIdx.x * 256 + threadIdx.x;
    if (s < NPAD) {
        unsigned long long rec;
        if (s < E) {
            int a = edges[s], b = edges[E + s];
            float k = __fadd_rn(pri[a], pri[b]);   // epri >= 0 -> bits monotone
            rec = ((unsigned long long)__float_as_uint(k) << 32) | (unsigned)s;
        } else {
            rec = (0xFFFFFFFFull << 32) | (unsigned)s;
        }
        keys[s] = rec;
    }
}

// bitonic sort one 8192-element half in LDS; 2 blocks run concurrently
__launch_bounds__(1024)
__global__ void k_sort2(unsigned long long* __restrict__ keys) {
    __shared__ unsigned long long srt[HALF];
    const int tid = threadIdx.x;
    unsigned long long* base = keys + blockIdx.x * HALF;
    for (int s = tid; s < HALF; s += 1024) srt[s] = base[s];
    __syncthreads();
    for (int k = 2; k <= HALF; k <<= 1) {
        for (int j = k >> 1; j >= 1; j >>= 1) {
            for (int i = tid; i < HALF; i += 1024) {
                int ixj = i ^ j;
                if (ixj > i) {
                    unsigned long long x = srt[i], y = srt[ixj];
                    bool up = ((i & k) == 0);
                    if ((x > y) == up) { srt[i] = y; srt[ixj] = x; }
                }
            }
            __syncthreads();
        }
    }
    for (int s = tid; s < HALF; s += 1024) base[s] = srt[s];
}

// merge-path the two sorted halves; emit packed (v0<<16|v1) in global order
__launch_bounds__(64)
__global__ void k_mergepath(const unsigned long long* __restrict__ keys,
                            const int* __restrict__ edges, unsigned* __restrict__ pkG) {
    int t = blockIdx.x * 64 + threadIdx.x;
    if (t >= E / 64) return;
    const unsigned long long* A = keys;
    const unsigned long long* B = keys + HALF;
    int d = t * 64;
    int lo = d > HALF ? d - HALF : 0;
    int hi = d < HALF ? d : HALF;
    while (lo < hi) {
        int mid = (lo + hi) >> 1;
        if (A[mid] < B[d - 1 - mid]) lo = mid + 1; else hi = mid;
    }
    int ia = lo, ib = d - lo;
    for (int o = d; o < d + 64; o++) {
        bool takeA = (ib >= HALF) || (ia < HALF && A[ia] < B[ib]);
        unsigned long long r = takeA ? A[ia++] : B[ib++];
        int e = (int)(r & 0xFFFFFFFFull);
        int a = edges[e], b = edges[E + e];
        pkG[o] = ((unsigned)a << 16) | (unsigned)b;
    }
}

// ONE wave: windowed scan + batched independent merges
__launch_bounds__(64)
__global__ void k_collapse(const unsigned* __restrict__ pkG, unsigned* n32,
                           unsigned* __restrict__ pairsG, int* __restrict__ mcountG,
                           uint8_t* __restrict__ aliveG, float* __restrict__ out) {
    __shared__ uint8_t alive[V];
    const int lane = threadIdx.x;
    for (int v = lane; v < V; v += 64) alive[v] = 1;
    __syncthreads();

    int cnt = V, mcount = 0;
    bool done = false;

    for (int w = 0; w < E && !done; w += 64) {
        unsigned pkv = pkG[w + lane];
        const int a = (int)(pkv >> 16), b = (int)(pkv & 0xFFFFu);
        const int widx = a * ROWU32 + (b >> 4);
        const int wsh = (b & 15) * 2;
        bool dec = false;

        while (!done) {
            // drain our stores/atomics, then re-evaluate undecided lanes from memory
            __builtin_amdgcn_s_waitcnt(0);
            bool av = alive[a] && alive[b];
            unsigned wv = ((volatile unsigned*)n32)[widx];
            bool flag = !dec && av && (((wv >> wsh) & 3u) == 2u);
            if (!dec && !av) dec = true;                    // dead -> reject forever

            // ---- in-order scan: accept vertex-disjoint candidates, poison deps ----
            bool pois = false, vis = false, accMe = false;
            unsigned long long accMask = 0ull;
            int nacc = 0;
            int limit = cnt - TARGET; if (limit > 8) limit = 8;
            int scanEnd = 64;
            while (true) {
                unsigned long long m = __ballot(!dec && !vis && (flag || pois));
                if (!m) break;
                int i = __ffsll(m) - 1;
                unsigned long long pb = __ballot(pois);
                int ai = __shfl(a, i), bi = __shfl(b, i);
                bool isP = (pb >> i) & 1ull;
                if (!isP) {
                    if (nacc < limit) {
                        accMask |= 1ull << i; nacc++;
                        if (lane == i) { dec = true; accMe = true; }
                    } else { scanEnd = i; break; }
                } else {
                    if (lane == i) vis = true;              // pending this round
                }
                if (lane > i && (a == ai || a == bi || b == ai || b == bi)) pois = true;
            }
            // reject unflagged, untouched lanes whose turn completed
            if (!dec && !vis && !pois && !flag && lane < scanEnd) dec = true;

            if (nacc == 0) break;                           // no flagged lanes -> window done

            // ---- batched row loads (one latency for all accepted merges) ----
            uint4 RA[8], RB[8];
            int MV0[8], MV1[8];
            {
                unsigned long long am = accMask;
#pragma unroll
                for (int jj = 0; jj < 8; jj++) {
                    if (jj < nacc) {
                        int lj = __ffsll(am) - 1; am &= am - 1ull;
                        int v0 = __shfl(a, lj), v1 = __shfl(b, lj);
                        MV0[jj] = v0; MV1[jj] = v1;
                        RA[jj] = *((const uint4*)(n32 + v0 * ROWU32) + lane);
                        RB[jj] = *((const uint4*)(n32 + v1 * ROWU32) + lane);
                    }
                }
            }

            // ---- adjacency-conflict filter: keep jj only if {v0,v1} not adjacent
            //      to any kept earlier dying vertex (else stale-register hazard) ----
            unsigned keptMask = 0;
            uint4 RBU = make_uint4(0u, 0u, 0u, 0u);
#pragma unroll
            for (int jj = 0; jj < 8; jj++) {
                if (jj < nacc) {
                    int v0 = MV0[jj], v1 = MV1[jj];
                    bool c = false;
                    if ((v0 >> 6) == lane)
                        c |= ((getf(RBU, (v0 >> 4) & 3) >> ((v0 & 15) * 2)) & 3u) != 0u;
                    if ((v1 >> 6) == lane)
                        c |= ((getf(RBU, (v1 >> 4) & 3) >> ((v1 & 15) * 2)) & 3u) != 0u;
                    if (__ballot(c) == 0ull) {
                        keptMask |= 1u << jj;
                        RBU.x |= RB[jj].x; RBU.y |= RB[jj].y;
                        RBU.z |= RB[jj].z; RBU.w |= RB[jj].w;
                    }
                }
            }
            // demote accepted-but-not-kept lanes back to undecided
            if (accMe) {
                int myjj = (int)__popcll(accMask & ((1ull << lane) - 1ull));
                if (!((keptMask >> myjj) & 1u)) dec = false;
            }

            // ---- apply kept merges (disjoint; saturating monoid commutes) ----
#pragma unroll
            for (int jj = 0; jj < 8; jj++) {
                if (jj < nacc && ((keptMask >> jj) & 1u)) {
                    int v0 = MV0[jj], v1 = MV1[jj];
                    uint4 ra = RA[jj], rb = RB[jj];
                    uint4 rr;
                    rr.x = ra.x | rb.x | ((ra.x & rb.x & 0xAAAAAAAAu) >> 1);
                    rr.y = ra.y | rb.y | ((ra.y & rb.y & 0xAAAAAAAAu) >> 1);
                    rr.z = ra.z | rb.z | ((ra.z & rb.z & 0xAAAAAAAAu) >> 1);
                    rr.w = ra.w | rb.w | ((ra.w & rb.w & 0xAAAAAAAAu) >> 1);
                    if ((v0 >> 6) == lane) {
                        unsigned msk = ~(3u << ((v0 & 15) * 2)); int c = (v0 >> 4) & 3;
                        if (c == 0) rr.x &= msk; else if (c == 1) rr.y &= msk;
                        else if (c == 2) rr.z &= msk; else rr.w &= msk;
                    }
                    if ((v1 >> 6) == lane) {
                        unsigned msk = ~(3u << ((v1 & 15) * 2)); int c = (v1 >> 4) & 3;
                        if (c == 0) rr.x &= msk; else if (c == 1) rr.y &= msk;
                        else if (c == 2) rr.z &= msk; else rr.w &= msk;
                    }
                    *((uint4*)(n32 + v0 * ROWU32) + lane) = rr;
                    // column fixups: n[x][v0] ^= old^new via symmetry (zero loads);
                    // dead row v1 left as-is (never read again)
                    int sh0 = (v0 & 15) * 2;
                    int wi0 = v0 >> 4;
#pragma unroll
                    for (int c = 0; c < 4; c++) {
                        unsigned bb = getf(rb, c);
                        if (!bb) continue;
                        unsigned aa = getf(ra, c);
                        unsigned vv = getf(rr, c);
                        int xbase = (lane << 6) + (c << 4);
                        unsigned t = bb;
                        while (t) {
                            int q = (__ffs(t) - 1) >> 1;
                            t &= ~(3u << (q * 2));
                            int x = xbase + q;
                            if (x != v0 && x != v1) {
                                unsigned o0  = (aa >> (q * 2)) & 3u;
                                unsigned val = (vv >> (q * 2)) & 3u;
                                unsigned dx = (o0 ^ val) << sh0;
                                if (dx) atomicXor(n32 + x * ROWU32 + wi0, dx);
                            }
                        }
                    }
                    if (lane == 0) {
                        alive[v1] = 0;
                        pairsG[mcount] = ((unsigned)v0 << 16) | (unsigned)v1;
                    }
                    mcount++; cnt--;
                }
            }
            if (cnt == TARGET) done = true;
            if (__ballot(!dec) == 0ull) break;              // window fully decided
        }
    }

    __builtin_amdgcn_s_waitcnt(0);
    for (int v = lane; v < V; v += 64) {
        uint8_t ao = alive[v];
        aliveG[v] = ao;
        out[V * D + v] = ao ? 1.0f : 0.0f;
    }
    if (lane == 0) { mcountG[0] = mcount; out[V * D + V] = (float)cnt; }
}

// Replay merge forest: per-vertex (root, weight) then scatter-add w*f[v] into out[root].
// Log order only permutes vertex-disjoint merges -> A-algebra result identical.
__launch_bounds__(256)
__global__ void k_apply(const float* __restrict__ f, const unsigned* __restrict__ pairsG,
                        const int* __restrict__ mcountG, float* __restrict__ out) {
    __shared__ unsigned pl[MAXM];
    __shared__ int rootL[256];
    __shared__ float wL[256];
    const int tid = threadIdx.x;
    const int mc = mcountG[0];
    for (int j = tid; j < mc; j += 256) pl[j] = pairsG[j];
    __syncthreads();
    int cur = blockIdx.x * 256 + tid;
    float w = 1.0f;
    for (int j = 0; j < mc; j++) {
        unsigned p = pl[j];
        int v0 = (int)(p >> 16), v1 = (int)(p & 0xFFFFu);
        if (cur == v1) { cur = v0; w *= 0.5f; }
        else if (cur == v0) w *= 0.5f;
    }
    rootL[tid] = cur;
    wL[tid] = w;
    __syncthreads();
    const int sub = tid >> 7;
    const int d = tid & 127;
    for (int s = 0; s < 256; s += 2) {
        int idx = s + sub;
        int vv = blockIdx.x * 256 + idx;
        atomicAdd(&out[rootL[idx] * D + d], wL[idx] * f[vv * D + d]);
    }
}

extern "C" void kernel_launch(void* const* d_in, const int* in_sizes, int n_in,
                              void* d_out, int out_size, void* d_ws, size_t ws_size,
                              hipStream_t stream) {
    (void)in_sizes; (void)n_in; (void)out_size; (void)ws_size;
    const float* features = (const float*)d_in[0];
    const int* edges = (const int*)d_in[1];
    uint8_t* ws = (uint8_t*)d_ws;
    unsigned* n32 = (unsigned*)(ws + WS_N);
    float* pri = (float*)(ws + WS_PRI);
    unsigned long long* keys = (unsigned long long*)(ws + WS_KEYS);
    unsigned* pkG = (unsigned*)(ws + WS_PK);
    unsigned* pairsG = (unsigned*)(ws + WS_PAIRS);
    int* mcountG = (int*)(ws + WS_MCOUNT);
    uint8_t* aliveG = ws + WS_ALIVE;
    float* out = (float*)d_out;

    hipMemsetAsync(n32, 0, (size_t)V * ROWU32 * 4, stream);
    hipMemsetAsync(out, 0, (size_t)V * D * sizeof(float), stream);
    k_pri<<<(V + 255) / 256, 256, 0, stream>>>(features, pri);
    k_scatter<<<(E + 255) / 256, 256, 0, stream>>>(edges, n32);
    k_keys<<<(NPAD + 255) / 256, 256, 0, stream>>>(edges, pri, keys);
    k_sort2<<<2, 1024, 0, stream>>>(keys);
    k_mergepath<<<(E / 64 + 63) / 64, 64, 0, stream>>>(keys, edges, pkG);
    k_collapse<<<1, 64, 0, stream>>>(pkG, n32, pairsG, mcountG, aliveG, out);
    k_apply<<<V / 256, 256, 0, stream>>>(features, pairsG, mcountG, out);
}